// Round 14
// baseline (15560.097 us; speedup 1.0000x reference)
//
#include <hip/hip_runtime.h>
#include <hip/hip_bf16.h>
#include <math.h>

#define L 4096
#define D 512
#define PP 64
#define HH 128
#define EPSF 1e-8f

typedef _Float16 f16x8 __attribute__((ext_vector_type(8)));
typedef float f32x4 __attribute__((ext_vector_type(4)));
typedef short bf16x8 __attribute__((ext_vector_type(8)));

__device__ __forceinline__ unsigned short f2b(float x) {
  uint32_t u = __float_as_uint(x);
  u += 0x7FFFu + ((u >> 16) & 1u);
  return (unsigned short)(u >> 16);
}
__device__ __forceinline__ float b2f(unsigned short s) {
  return __uint_as_float(((uint32_t)s) << 16);
}

// ---------------- norms: ||p_l||, ||h_l|| ----------------
__global__ __launch_bounds__(64) void norms_kernel(const float* __restrict__ fp, const float* __restrict__ fh,
                                                   float* __restrict__ np_, float* __restrict__ nh_) {
  int b = blockIdx.x;
  int which = b >> 12;
  int l = b & (L - 1);
  const float* v = (which ? fh : fp) + (size_t)l * D;
  float s = 0.f;
  for (int i = threadIdx.x; i < D; i += 64) { float x = v[i]; s += x * x; }
  for (int off = 32; off > 0; off >>= 1) s += __shfl_down(s, off);
  if (threadIdx.x == 0) (which ? nh_ : np_)[l] = sqrtf(s);
}

// ---------------- bf16 casts of feature_p / feature_h ----------------
__global__ __launch_bounds__(256) void cast_kernel(const float* __restrict__ fp, const float* __restrict__ fh,
                                                   unsigned short* __restrict__ fpb, unsigned short* __restrict__ fhb) {
  int which = blockIdx.y;
  const float* src = which ? fh : fp;
  unsigned short* dst = which ? fhb : fpb;
  size_t base = ((size_t)blockIdx.x * 256 + threadIdx.x) * 8;
  float4 a = *reinterpret_cast<const float4*>(&src[base]);
  float4 b = *reinterpret_cast<const float4*>(&src[base + 4]);
  unsigned short u[8];
  u[0] = f2b(a.x); u[1] = f2b(a.y); u[2] = f2b(a.z); u[3] = f2b(a.w);
  u[4] = f2b(b.x); u[5] = f2b(b.y); u[6] = f2b(b.z); u[7] = f2b(b.w);
  *reinterpret_cast<uint4*>(&dst[base]) = *reinterpret_cast<uint4*>(u);
}

// ---------------- transposed bf16 casts: fpbt[d][l] = fp[l][d] ----------------
__global__ __launch_bounds__(256) void transp_kernel(const float* __restrict__ fp, const float* __restrict__ fh,
                                                     unsigned short* __restrict__ fpbt, unsigned short* __restrict__ fhbt) {
  int which = blockIdx.z;
  const float* src = which ? fh : fp;
  unsigned short* dst = which ? fhbt : fpbt;
  __shared__ __align__(16) unsigned short tile[64][68];
  int d0 = blockIdx.x * 64, l0 = blockIdx.y * 64;
  int t = threadIdx.x;
#pragma unroll
  for (int i = 0; i < 4; i++) {
    int idx = t + i * 256;                 // 1024 float4-chunks
    int r = idx >> 4, c4 = idx & 15;
    float4 v = *reinterpret_cast<const float4*>(&src[(size_t)(l0 + r) * D + d0 + c4 * 4]);
    unsigned short u[4] = {f2b(v.x), f2b(v.y), f2b(v.z), f2b(v.w)};
    *reinterpret_cast<uint2*>(&tile[r][c4 * 4]) = *reinterpret_cast<uint2*>(u);
  }
  __syncthreads();
#pragma unroll
  for (int i = 0; i < 2; i++) {
    int idx = t + i * 256;                 // 512 out-chunks of 8
    int dd = idx >> 3, cc = idx & 7;
    unsigned short u[8];
#pragma unroll
    for (int e = 0; e < 8; e++) u[e] = tile[cc * 8 + e][dd];
    *reinterpret_cast<uint4*>(&dst[(size_t)(d0 + dd) * L + l0 + cc * 8]) = *reinterpret_cast<uint4*>(u);
  }
}

// ---------------- att (bf16 MFMA): att_b = bf16((fpb @ fhb^T)/clamp(np*nh)) ----
__global__ __launch_bounds__(256) void attb_kernel(const unsigned short* __restrict__ fpb,
                                                   const unsigned short* __restrict__ fhb,
                                                   const float* __restrict__ np_, const float* __restrict__ nh_,
                                                   unsigned short* __restrict__ att_b) {
  __shared__ __align__(16) unsigned short As[128][72];
  __shared__ __align__(16) unsigned short Bs[64][72];
  const int t = threadIdx.x, lane = t & 63, wid = t >> 6;
  const int wm = wid >> 1, wn = wid & 1, r = lane & 15, ks = lane >> 4;
  const int row0 = blockIdx.y * 128, col0 = blockIdx.x * 64;
  f32x4 acc[4][2] = {};
  for (int k0 = 0; k0 < D; k0 += 64) {
#pragma unroll
    for (int i = 0; i < 4; i++) {
      int idx = t + i * 256; int row = idx >> 3, c8 = idx & 7;
      uint4 v = *reinterpret_cast<const uint4*>(&fpb[(size_t)(row0 + row) * D + k0 + c8 * 8]);
      *reinterpret_cast<uint4*>(&As[row][c8 * 8]) = v;
    }
#pragma unroll
    for (int i = 0; i < 2; i++) {
      int idx = t + i * 256; int col = idx >> 3, c8 = idx & 7;
      uint4 v = *reinterpret_cast<const uint4*>(&fhb[(size_t)(col0 + col) * D + k0 + c8 * 8]);
      *reinterpret_cast<uint4*>(&Bs[col][c8 * 8]) = v;
    }
    __syncthreads();
#pragma unroll
    for (int k2 = 0; k2 < 2; k2++) {
      bf16x8 b0 = *reinterpret_cast<const bf16x8*>(&Bs[wn * 32 + r][k2 * 32 + ks * 8]);
      bf16x8 b1 = *reinterpret_cast<const bf16x8*>(&Bs[wn * 32 + 16 + r][k2 * 32 + ks * 8]);
#pragma unroll
      for (int fm = 0; fm < 4; fm++) {
        bf16x8 a = *reinterpret_cast<const bf16x8*>(&As[wm * 64 + fm * 16 + r][k2 * 32 + ks * 8]);
        acc[fm][0] = __builtin_amdgcn_mfma_f32_16x16x32_bf16(a, b0, acc[fm][0], 0, 0, 0);
        acc[fm][1] = __builtin_amdgcn_mfma_f32_16x16x32_bf16(a, b1, acc[fm][1], 0, 0, 0);
      }
    }
    __syncthreads();
  }
#pragma unroll
  for (int fm = 0; fm < 4; fm++)
#pragma unroll
    for (int fn = 0; fn < 2; fn++)
#pragma unroll
      for (int reg = 0; reg < 4; reg++) {
        int l = row0 + wm * 64 + fm * 16 + ks * 4 + reg;
        int c = col0 + wn * 32 + fn * 16 + r;
        float den = np_[l] * nh_[c];
        den = den > EPSF ? den : EPSF;
        att_b[(size_t)l * L + c] = f2b(acc[fm][fn][reg] / den);
      }
}

// ---------------- row sums of att_b (bf16) ----------------
__global__ __launch_bounds__(256) void rowsum_kernel(const unsigned short* __restrict__ att_b, float* __restrict__ rs) {
  int row = blockIdx.x;
  float s = 0.f;
#pragma unroll
  for (int i = 0; i < 2; i++) {
    int chunk = threadIdx.x + i * 256;
    uint4 v = *reinterpret_cast<const uint4*>(&att_b[(size_t)row * L + chunk * 8]);
    const unsigned short* u = reinterpret_cast<const unsigned short*>(&v);
#pragma unroll
    for (int e = 0; e < 8; e++) s += b2f(u[e]);
  }
  for (int off = 32; off > 0; off >>= 1) s += __shfl_down(s, off);
  __shared__ float ps[4];
  if ((threadIdx.x & 63) == 0) ps[threadIdx.x >> 6] = s;
  __syncthreads();
  if (threadIdx.x == 0) rs[row] = ps[0] + ps[1] + ps[2] + ps[3];
}

// ---------------- column sums of att_b (2-stage, deterministic) ----------------
__global__ __launch_bounds__(256) void colpart_kernel(const unsigned short* __restrict__ att_b, float* __restrict__ pr) {
  int bx = blockIdx.x & 15, by = blockIdx.x >> 4;
  int col = bx * 256 + threadIdx.x;
  int r0 = by * 64;
  float s = 0.f;
#pragma unroll 8
  for (int r = 0; r < 64; r++) s += b2f(att_b[(size_t)(r0 + r) * L + col]);
  pr[(size_t)by * L + col] = s;
}
__global__ __launch_bounds__(256) void colsum_kernel(const float* __restrict__ pr, float* __restrict__ cs) {
  int col = blockIdx.x * 256 + threadIdx.x;
  float s = 0.f;
#pragma unroll 8
  for (int k = 0; k < 64; k++) s += pr[(size_t)k * L + col];
  cs[col] = s;
}

// ---------------- amh = (att_b @ fh) / clamp(rs)  [B from fhbt, B^T-form] ----
__global__ __launch_bounds__(256) void amh_kernel(const unsigned short* __restrict__ att_b,
                                                  const unsigned short* __restrict__ fhbt,
                                                  const float* __restrict__ rs, float* __restrict__ outm) {
  __shared__ __align__(16) unsigned short As[128][72];
  __shared__ __align__(16) unsigned short Bs[64][72];
  const int t = threadIdx.x, lane = t & 63, wid = t >> 6;
  const int wm = wid >> 1, wn = wid & 1, r = lane & 15, ks = lane >> 4;
  const int row0 = blockIdx.y * 128, col0 = blockIdx.x * 64;
  f32x4 acc[4][2] = {};
  for (int k0 = 0; k0 < L; k0 += 64) {
#pragma unroll
    for (int i = 0; i < 4; i++) {
      int idx = t + i * 256; int row = idx >> 3, c8 = idx & 7;
      uint4 v = *reinterpret_cast<const uint4*>(&att_b[(size_t)(row0 + row) * L + k0 + c8 * 8]);
      *reinterpret_cast<uint4*>(&As[row][c8 * 8]) = v;
    }
#pragma unroll
    for (int i = 0; i < 2; i++) {
      int idx = t + i * 256; int col = idx >> 3, c8 = idx & 7;
      uint4 v = *reinterpret_cast<const uint4*>(&fhbt[(size_t)(col0 + col) * L + k0 + c8 * 8]);
      *reinterpret_cast<uint4*>(&Bs[col][c8 * 8]) = v;
    }
    __syncthreads();
#pragma unroll
    for (int k2 = 0; k2 < 2; k2++) {
      bf16x8 b0 = *reinterpret_cast<const bf16x8*>(&Bs[wn * 32 + r][k2 * 32 + ks * 8]);
      bf16x8 b1 = *reinterpret_cast<const bf16x8*>(&Bs[wn * 32 + 16 + r][k2 * 32 + ks * 8]);
#pragma unroll
      for (int fm = 0; fm < 4; fm++) {
        bf16x8 a = *reinterpret_cast<const bf16x8*>(&As[wm * 64 + fm * 16 + r][k2 * 32 + ks * 8]);
        acc[fm][0] = __builtin_amdgcn_mfma_f32_16x16x32_bf16(a, b0, acc[fm][0], 0, 0, 0);
        acc[fm][1] = __builtin_amdgcn_mfma_f32_16x16x32_bf16(a, b1, acc[fm][1], 0, 0, 0);
      }
    }
    __syncthreads();
  }
#pragma unroll
  for (int fm = 0; fm < 4; fm++)
#pragma unroll
    for (int fn = 0; fn < 2; fn++)
#pragma unroll
      for (int reg = 0; reg < 4; reg++) {
        int l = row0 + wm * 64 + fm * 16 + ks * 4 + reg;
        int d = col0 + wn * 32 + fn * 16 + r;
        float den = rs[l];
        den = den > EPSF ? den : EPSF;
        outm[(size_t)l * D + d] = acc[fm][fn][reg] / den;
      }
}

// ---------------- amp = (att_b^T @ fp) / clamp(cs) [A transpose-staged] ------
__global__ __launch_bounds__(256) void amp_kernel(const unsigned short* __restrict__ att_b,
                                                  const unsigned short* __restrict__ fpbt,
                                                  const float* __restrict__ cs, float* __restrict__ outm) {
  __shared__ __align__(16) unsigned short At[128 * 72];   // swizzled k within rows
  __shared__ __align__(16) unsigned short Bs[64][72];
  const int t = threadIdx.x, lane = t & 63, wid = t >> 6;
  const int wm = wid >> 1, wn = wid & 1, r = lane & 15, ks = lane >> 4;
  const int row0 = blockIdx.y * 128, col0 = blockIdx.x * 64;
  f32x4 acc[4][2] = {};
  for (int k0 = 0; k0 < L; k0 += 64) {
#pragma unroll
    for (int i = 0; i < 4; i++) {
      int idx = t + i * 256;               // 1024 chunks: 64 kk x 16 c8
      int kk = idx >> 4, c8 = idx & 15;
      uint4 v = *reinterpret_cast<const uint4*>(&att_b[(size_t)(k0 + kk) * L + row0 + c8 * 8]);
      const unsigned short* u = reinterpret_cast<const unsigned short*>(&v);
      int swz = (c8 & 7) << 3;
#pragma unroll
      for (int e = 0; e < 8; e++)
        At[(c8 * 8 + e) * 72 + (kk ^ swz)] = u[e];
    }
#pragma unroll
    for (int i = 0; i < 2; i++) {
      int idx = t + i * 256; int col = idx >> 3, c8 = idx & 7;
      uint4 v = *reinterpret_cast<const uint4*>(&fpbt[(size_t)(col0 + col) * L + k0 + c8 * 8]);
      *reinterpret_cast<uint4*>(&Bs[col][c8 * 8]) = v;
    }
    __syncthreads();
#pragma unroll
    for (int k2 = 0; k2 < 2; k2++) {
      bf16x8 b0 = *reinterpret_cast<const bf16x8*>(&Bs[wn * 32 + r][k2 * 32 + ks * 8]);
      bf16x8 b1 = *reinterpret_cast<const bf16x8*>(&Bs[wn * 32 + 16 + r][k2 * 32 + ks * 8]);
#pragma unroll
      for (int fm = 0; fm < 4; fm++) {
        int j = wm * 64 + fm * 16 + r;
        int off = (k2 * 32 + ks * 8) ^ (((j >> 3) & 7) << 3);
        bf16x8 a = *reinterpret_cast<const bf16x8*>(&At[j * 72 + off]);
        acc[fm][0] = __builtin_amdgcn_mfma_f32_16x16x32_bf16(a, b0, acc[fm][0], 0, 0, 0);
        acc[fm][1] = __builtin_amdgcn_mfma_f32_16x16x32_bf16(a, b1, acc[fm][1], 0, 0, 0);
      }
    }
    __syncthreads();
  }
#pragma unroll
  for (int fm = 0; fm < 4; fm++)
#pragma unroll
    for (int fn = 0; fn < 2; fn++)
#pragma unroll
      for (int reg = 0; reg < 4; reg++) {
        int j = row0 + wm * 64 + fm * 16 + ks * 4 + reg;
        int d = col0 + wn * 32 + fn * 16 + r;
        float den = cs[j];
        den = den > EPSF ? den : EPSF;
        outm[(size_t)j * D + d] = acc[fm][fn][reg] / den;
      }
}

// ---------------- w2 transposed: w2t[d][p] = mp_w[p][d]^2 ----------------
__global__ void w2t_kernel(const float* __restrict__ mpw, float* __restrict__ w2t) {
  int o = blockIdx.x * blockDim.x + threadIdx.x;
  if (o >= PP * D) return;
  int dd = o >> 6, p = o & 63;
  float v = mpw[(size_t)p * D + dd];
  w2t[o] = v * v;
}

// ---------------- multi-perspective weighted cosine ----------------
__global__ __launch_bounds__(64) void match_kernel(const float* __restrict__ fp, const float* __restrict__ fh,
                                                   const float* __restrict__ amh, const float* __restrict__ amp,
                                                   const float* __restrict__ w2t,
                                                   float* __restrict__ match_p, float* __restrict__ match_h) {
  int b = blockIdx.x;
  int which = b >> 12;
  int l = b & (L - 1);
  const float* v1 = (which ? fh : fp) + (size_t)l * D;
  const float* v2 = (which ? amp : amh) + (size_t)l * D;
  __shared__ float s1[D], s2[D];
  int t = threadIdx.x;
#pragma unroll
  for (int i = 0; i < 2; i++) {
    int f4 = t + 64 * i;
    *reinterpret_cast<float4*>(&s1[f4 * 4]) = *reinterpret_cast<const float4*>(&v1[f4 * 4]);
    *reinterpret_cast<float4*>(&s2[f4 * 4]) = *reinterpret_cast<const float4*>(&v2[f4 * 4]);
  }
  __syncthreads();
  float num = 0.f, a1 = 0.f, a2 = 0.f;
  for (int dd = 0; dd < D; dd++) {
    float wv = w2t[dd * PP + t];
    float x = s1[dd], y = s2[dd];
    num += wv * x * y;
    a1 += wv * x * x;
    a2 += wv * y * y;
  }
  float n1 = fmaxf(sqrtf(a1), EPSF), n2 = fmaxf(sqrtf(a2), EPSF);
  float* outm = which ? match_h : match_p;
  outm[(size_t)l * PP + t] = num / (n1 * n2);
}

// ---------------- gx = match @ w_ih^T + (b_ih + b_hh) ----------------
// Time-reversed for odd dirs AND stored in the lstm kernel's lane-order
// (verified correct in round 12): for output j (gate = j>>7, m = j&127,
// w = m>>3, rem = m&7, c = rem>>2, ks = rem&3), slot = (w*4+ks)*8 + c*4 + gate.
__global__ __launch_bounds__(512) void gx_kernel(const float* __restrict__ match_p, const float* __restrict__ match_h,
                                                 const float* __restrict__ wih_f, const float* __restrict__ wih_r,
                                                 const float* __restrict__ bih_f, const float* __restrict__ bhh_f,
                                                 const float* __restrict__ bih_r, const float* __restrict__ bhh_r,
                                                 float* __restrict__ gx) {
  int b = blockIdx.x;
  int dir = b >> 9;
  int chunk = b & 511;
  const float* m_src = (dir < 2) ? match_p : match_h;
  const float* wih = (dir & 1) ? wih_r : wih_f;
  const float* bi = (dir & 1) ? bih_r : bih_f;
  const float* bh = (dir & 1) ? bhh_r : bhh_f;
  __shared__ float m[8][PP];
  int t = threadIdx.x;
  {
    int tt = t >> 6, p = t & 63;
    int tstep = chunk * 8 + tt;
    int row = (dir & 1) ? (L - 1 - tstep) : tstep;
    m[tt][p] = m_src[(size_t)row * PP + p];
  }
  __syncthreads();
  int j = t;
  float bias = bi[j] + bh[j];
  float acc[8];
#pragma unroll
  for (int tt = 0; tt < 8; tt++) acc[tt] = bias;
  for (int p = 0; p < PP; p++) {
    float wv = wih[(size_t)j * PP + p];
#pragma unroll
    for (int tt = 0; tt < 8; tt++) acc[tt] += wv * m[tt][p];
  }
  int gate = j >> 7, mm = j & 127;
  int wvv = mm >> 3, rem = mm & 7, cc = rem >> 2, ks = rem & 3;
  int idx = (wvv * 4 + ks) * 8 + cc * 4 + gate;
#pragma unroll
  for (int tt = 0; tt < 8; tt++)
    gx[((size_t)dir * L + chunk * 8 + tt) * 512 + idx] = acc[tt];
}

// load 8 consecutive fp32 weights, convert+pack to f16x8 (MFMA A-fragment).
__device__ __forceinline__ f16x8 ldw(const float* p) {
  float4 a = *reinterpret_cast<const float4*>(p);
  float4 b = *reinterpret_cast<const float4*>(p + 4);
  f16x8 o;
  o[0] = (_Float16)a.x; o[1] = (_Float16)a.y; o[2] = (_Float16)a.z; o[3] = (_Float16)a.w;
  o[4] = (_Float16)b.x; o[5] = (_Float16)b.y; o[6] = (_Float16)b.z; o[7] = (_Float16)b.w;
  return o;
}

// LDS-only barrier: drain lgkmcnt, raw s_barrier; vmcnt stays in flight.
__device__ __forceinline__ void lds_barrier() {
  asm volatile("s_waitcnt lgkmcnt(0)" ::: "memory");
  __builtin_amdgcn_s_barrier();
}

__device__ __forceinline__ float sigm(float z) { return 1.f / (1.f + __expf(-z)); }
__device__ __forceinline__ float tanh2(float z) { float e = __expf(2.f * z); return 1.f - 2.f / (e + 1.f); }

// stage one 512-float gx row into LDS via global_load_lds (2 x 16B/lane).
__device__ __forceinline__ void stage_row(const float* rowbase, float* lp, int lane) {
  const float* g1 = rowbase + lane * 4;
  const float* g2 = rowbase + 256 + lane * 4;
  __builtin_amdgcn_global_load_lds((const __attribute__((address_space(1))) void*)g1,
                                   (__attribute__((address_space(3))) void*)lp, 16, 0, 0);
  __builtin_amdgcn_global_load_lds((const __attribute__((address_space(1))) void*)g2,
                                   (__attribute__((address_space(3))) void*)(lp + 256), 16, 0, 0);
}

// ---------------- 4 sequential LSTMs — gate-grouped MFMA, 1 barrier/step ----
// r12's structure (verified numerically correct there) with its register-
// pressure flaw fixed: gx lives in a triple-buffered LDS ring staged by wave 0
// via global_load_lds (counted vmcnt(2), prefetch distance 2) instead of in
// per-lane float4 registers (+16 live VGPRs was what spilled r12 to scratch:
// allocator pins ~52 VGPRs and scratch-spills excess — the 6-15x regression).
// A-row mapping: row rl of wave wv -> output j = ((rl&3)<<7) + 8wv + (rl>>2),
// so col-0 lane ksub holds ALL FOUR gate pre-activations of m = 8wv+ksub
// (chain A) and m+4 (chain B) in accumulator registers -> in-register
// activations + c/h update, no z LDS round-trip, ONE lds_barrier per step.
// B-operand: per-lane base -> h fragment for col-0 lanes, shared zero region
// for the rest (broadcast read, no cndmasks, conflict-free).
__global__ __attribute__((amdgpu_waves_per_eu(4, 4))) __launch_bounds__(1024)
void lstm_kernel(const float* __restrict__ gx,
                 const float* __restrict__ whh_f, const float* __restrict__ whh_r,
                 float* __restrict__ out) {
  const int dir = blockIdx.x;
  const float* __restrict__ whh = (dir & 1) ? whh_r : whh_f;
  const int tid = threadIdx.x;
  const int lane = tid & 63;
  const int wv = tid >> 6;            // wave 0..15
  const int rl = lane & 15;           // A row-lane / B col
  const int ksub = lane >> 4;         // k subgroup 0..3
  const int jA = ((rl & 3) << 7) + 8 * wv + (rl >> 2);
  const int jB = jA + 4;
  const float* baseA = whh + (size_t)jA * HH + ksub * 8;
  const float* baseB = whh + (size_t)jB * HH + ksub * 8;
  f16x8 wA0 = ldw(baseA);       f16x8 wA1 = ldw(baseA + 32);
  f16x8 wA2 = ldw(baseA + 64);  f16x8 wA3 = ldw(baseA + 96);
  f16x8 wB0 = ldw(baseB);       f16x8 wB1 = ldw(baseB + 32);
  f16x8 wB2 = ldw(baseB + 64);  f16x8 wB3 = ldw(baseB + 96);

  __shared__ __align__(16) _Float16 hbuf[2][HH];   // double-buffered h (fp16)
  __shared__ __align__(16) _Float16 hz[HH];        // permanent zeros
  __shared__ __align__(16) float gxl[3][512];      // gx ring (6 KB)
  if (tid < HH) {
    hbuf[0][tid] = (_Float16)0.f;
    hbuf[1][tid] = (_Float16)0.f;
    hz[tid] = (_Float16)0.f;
  }

  const float* __restrict__ gsrc = gx + (size_t)dir * L * 512;
  const bool act = (rl == 0);
  const int mA = 8 * wv + ksub, mB = mA + 4;
  const int a8 = (wv * 4 + ksub) * 8;

  // prologue: stage rows 0,1; wait for row 0 (2 newest may stay in flight)
  if (wv == 0) {
    stage_row(gsrc, &gxl[0][0], lane);
    stage_row(gsrc + 512, &gxl[1][0], lane);
    asm volatile("s_waitcnt vmcnt(2)" ::: "memory");
  }
  lds_barrier();

  const _Float16* pb0 = act ? &hbuf[0][ksub * 8] : hz;
  const _Float16* pb1 = act ? &hbuf[1][ksub * 8] : hz;
  float cA = 0.f, cB = 0.f, hA = 0.f, hB = 0.f;
  int bcur = 0, bstg = 2;

  for (int t = 0; t < L; t++) {
    // gx for this step (LDS, ready since last barrier); read early, used late
    float4 gxA, gxB;
    if (act) {
      const float* gl = &gxl[bcur][a8];
      gxA = *reinterpret_cast<const float4*>(gl);
      gxB = *reinterpret_cast<const float4*>(gl + 4);
    }
    // wave 0: stage step t+2's row (stays in flight across the barrier)
    if (wv == 0) {
      int trow = (t + 2 < L) ? (t + 2) : (L - 1);
      stage_row(gsrc + (size_t)trow * 512, &gxl[bstg][0], lane);
    }
    const _Float16* hb = (t & 1) ? pb1 : pb0;
    f32x4 accA = {0.f, 0.f, 0.f, 0.f};
    f32x4 accB = {0.f, 0.f, 0.f, 0.f};
#define CHUNK(q, WA, WB)                                                        \
    {                                                                           \
      uint4 raw = *reinterpret_cast<const uint4*>(hb + (q) * 32);               \
      f16x8 bf = __builtin_bit_cast(f16x8, raw);                                \
      accA = __builtin_amdgcn_mfma_f32_16x16x32_f16(WA, bf, accA, 0, 0, 0);     \
      accB = __builtin_amdgcn_mfma_f32_16x16x32_f16(WB, bf, accB, 0, 0, 0);     \
    }
    CHUNK(0, wA0, wB0)
    CHUNK(1, wA1, wB1)
    CHUNK(2, wA2, wB2)
    CHUNK(3, wA3, wB3)
#undef CHUNK
    if (act) {
      // accA[reg] = z_gate(reg) of mA; accB of mB — all in registers
      float iv = sigm(accA[0] + gxA.x);
      float fv = sigm(accA[1] + gxA.y);
      float gv = tanh2(accA[2] + gxA.z);
      float ov = sigm(accA[3] + gxA.w);
      cA = fv * cA + iv * gv;
      hA = ov * tanh2(cA);
      float iv2 = sigm(accB[0] + gxB.x);
      float fv2 = sigm(accB[1] + gxB.y);
      float gv2 = tanh2(accB[2] + gxB.z);
      float ov2 = sigm(accB[3] + gxB.w);
      cB = fv2 * cB + iv2 * gv2;
      hB = ov2 * tanh2(cB);
      int nxt = (t + 1) & 1;
      hbuf[nxt][mA] = (_Float16)hA;
      hbuf[nxt][mB] = (_Float16)hB;
    }
    // wave 0: allow the 2 just-issued loads to stay in flight; older must land
    if (wv == 0) asm volatile("s_waitcnt vmcnt(2)" ::: "memory");
    lds_barrier();
    bcur = (bcur == 2) ? 0 : bcur + 1;
    bstg = (bstg == 2) ? 0 : bstg + 1;
  }
  if (act) {
    out[dir * HH + mA] = hA;
    out[dir * HH + mB] = hB;
  }
}

extern "C" void kernel_launch(void* const* d_in, const int* in_sizes, int n_in,
                              void* d_out, int out_size, void* d_ws, size_t ws_size,
                              hipStream_t stream) {
  const float* fp    = (const float*)d_in[0];
  const float* fh    = (const float*)d_in[1];
  const float* mpw   = (const float*)d_in[2];
  const float* wih_f = (const float*)d_in[3];
  const float* whh_f = (const float*)d_in[4];
  const float* bih_f = (const float*)d_in[5];
  const float* bhh_f = (const float*)d_in[6];
  const float* wih_r = (const float*)d_in[7];
  const float* whh_r = (const float*)d_in[8];
  const float* bih_r = (const float*)d_in[9];
  const float* bhh_r = (const float*)d_in[10];
  float* out = (float*)d_out;
  float* ws = (float*)d_ws;

  // workspace layout (float units)
  size_t np_off   = 0;                          // 4096
  size_t nh_off   = np_off + L;                 // 4096
  size_t rs_off   = nh_off + L;                 // 4096
  size_t cs_off   = rs_off + L;                 // 4096
  size_t w2_off   = cs_off + L;                 // 32768
  size_t amh_off  = w2_off + (size_t)PP * D;    // 2097152
  size_t amp_off  = amh_off + (size_t)L * D;    // 2097152
  size_t mp_off   = amp_off + (size_t)L * D;    // 262144
  size_t mh_off   = mp_off + (size_t)L * PP;    // 262144
  size_t pr_off   = mh_off + (size_t)L * PP;    // 262144
  size_t fpb_off  = pr_off + (size_t)64 * L;    // bf16 buffers (L*D/2 floats each)
  size_t fhb_off  = fpb_off + (size_t)L * D / 2;
  size_t fpbt_off = fhb_off + (size_t)L * D / 2;
  size_t fhbt_off = fpbt_off + (size_t)L * D / 2;
  size_t attb_off = fhbt_off + (size_t)L * D / 2;  // L*L bf16 = L*L/2 floats
  size_t gx_off   = attb_off;                      // alias: gx reuses att_b region
  size_t total    = attb_off + (size_t)L * L / 2;
  {
    size_t gx_end = gx_off + (size_t)4 * L * 512;
    if (gx_end > total) total = gx_end;
  }
  if (ws_size < total * sizeof(float)) return;  // workspace too small — bail safely

  float* np_  = ws + np_off;
  float* nh_  = ws + nh_off;
  float* rs   = ws + rs_off;
  float* cs   = ws + cs_off;
  float* w2t  = ws + w2_off;
  float* amh  = ws + amh_off;
  float* amp  = ws + amp_off;
  float* mtp  = ws + mp_off;
  float* mth  = ws + mh_off;
  float* pr   = ws + pr_off;
  unsigned short* fpb  = (unsigned short*)(ws + fpb_off);
  unsigned short* fhb  = (unsigned short*)(ws + fhb_off);
  unsigned short* fpbt = (unsigned short*)(ws + fpbt_off);
  unsigned short* fhbt = (unsigned short*)(ws + fhbt_off);
  unsigned short* attb = (unsigned short*)(ws + attb_off);
  float* gx   = ws + gx_off;

  norms_kernel<<<2 * L, 64, 0, stream>>>(fp, fh, np_, nh_);
  cast_kernel<<<dim3((L * D) / (256 * 8), 2), 256, 0, stream>>>(fp, fh, fpb, fhb);
  transp_kernel<<<dim3(D / 64, L / 64, 2), 256, 0, stream>>>(fp, fh, fpbt, fhbt);
  attb_kernel<<<dim3(L / 64, L / 128), 256, 0, stream>>>(fpb, fhb, np_, nh_, attb);
  rowsum_kernel<<<L, 256, 0, stream>>>(attb, rs);
  colpart_kernel<<<1024, 256, 0, stream>>>(attb, pr);
  colsum_kernel<<<16, 256, 0, stream>>>(pr, cs);
  amh_kernel<<<dim3(D / 64, L / 128), 256, 0, stream>>>(attb, fhbt, rs, amh);
  amp_kernel<<<dim3(D / 64, L / 128), 256, 0, stream>>>(attb, fpbt, cs, amp);
  w2t_kernel<<<(PP * D + 255) / 256, 256, 0, stream>>>(mpw, w2t);
  match_kernel<<<2 * L, 64, 0, stream>>>(fp, fh, amh, amp, w2t, mtp, mth);
  gx_kernel<<<4 * (L / 8), 512, 0, stream>>>(mtp, mth, wih_f, wih_r, bih_f, bhh_f, bih_r, bhh_r, gx);
  lstm_kernel<<<4, 1024, 0, stream>>>(gx, whh_f, whh_r, out);
}

// Round 15
// 3522.544 us; speedup vs baseline: 4.4173x; 4.4173x over previous
//
#include <hip/hip_runtime.h>
#include <hip/hip_bf16.h>
#include <math.h>

#define L 4096
#define D 512
#define PP 64
#define HH 128
#define EPSF 1e-8f

typedef float f32x4 __attribute__((ext_vector_type(4)));
typedef short bf16x8 __attribute__((ext_vector_type(8)));

__device__ __forceinline__ unsigned short f2b(float x) {
  uint32_t u = __float_as_uint(x);
  u += 0x7FFFu + ((u >> 16) & 1u);
  return (unsigned short)(u >> 16);
}
__device__ __forceinline__ float b2f(unsigned short s) {
  return __uint_as_float(((uint32_t)s) << 16);
}

// ---------------- norms: ||p_l||, ||h_l|| ----------------
__global__ __launch_bounds__(64) void norms_kernel(const float* __restrict__ fp, const float* __restrict__ fh,
                                                   float* __restrict__ np_, float* __restrict__ nh_) {
  int b = blockIdx.x;
  int which = b >> 12;
  int l = b & (L - 1);
  const float* v = (which ? fh : fp) + (size_t)l * D;
  float s = 0.f;
  for (int i = threadIdx.x; i < D; i += 64) { float x = v[i]; s += x * x; }
  for (int off = 32; off > 0; off >>= 1) s += __shfl_down(s, off);
  if (threadIdx.x == 0) (which ? nh_ : np_)[l] = sqrtf(s);
}

// ---------------- bf16 casts of feature_p / feature_h ----------------
__global__ __launch_bounds__(256) void cast_kernel(const float* __restrict__ fp, const float* __restrict__ fh,
                                                   unsigned short* __restrict__ fpb, unsigned short* __restrict__ fhb) {
  int which = blockIdx.y;
  const float* src = which ? fh : fp;
  unsigned short* dst = which ? fhb : fpb;
  size_t base = ((size_t)blockIdx.x * 256 + threadIdx.x) * 8;
  float4 a = *reinterpret_cast<const float4*>(&src[base]);
  float4 b = *reinterpret_cast<const float4*>(&src[base + 4]);
  unsigned short u[8];
  u[0] = f2b(a.x); u[1] = f2b(a.y); u[2] = f2b(a.z); u[3] = f2b(a.w);
  u[4] = f2b(b.x); u[5] = f2b(b.y); u[6] = f2b(b.z); u[7] = f2b(b.w);
  *reinterpret_cast<uint4*>(&dst[base]) = *reinterpret_cast<uint4*>(u);
}

// ---------------- transposed bf16 casts: fpbt[d][l] = fp[l][d] ----------------
__global__ __launch_bounds__(256) void transp_kernel(const float* __restrict__ fp, const float* __restrict__ fh,
                                                     unsigned short* __restrict__ fpbt, unsigned short* __restrict__ fhbt) {
  int which = blockIdx.z;
  const float* src = which ? fh : fp;
  unsigned short* dst = which ? fhbt : fpbt;
  __shared__ __align__(16) unsigned short tile[64][68];
  int d0 = blockIdx.x * 64, l0 = blockIdx.y * 64;
  int t = threadIdx.x;
#pragma unroll
  for (int i = 0; i < 4; i++) {
    int idx = t + i * 256;                 // 1024 float4-chunks
    int r = idx >> 4, c4 = idx & 15;
    float4 v = *reinterpret_cast<const float4*>(&src[(size_t)(l0 + r) * D + d0 + c4 * 4]);
    unsigned short u[4] = {f2b(v.x), f2b(v.y), f2b(v.z), f2b(v.w)};
    *reinterpret_cast<uint2*>(&tile[r][c4 * 4]) = *reinterpret_cast<uint2*>(u);
  }
  __syncthreads();
#pragma unroll
  for (int i = 0; i < 2; i++) {
    int idx = t + i * 256;                 // 512 out-chunks of 8
    int dd = idx >> 3, cc = idx & 7;
    unsigned short u[8];
#pragma unroll
    for (int e = 0; e < 8; e++) u[e] = tile[cc * 8 + e][dd];
    *reinterpret_cast<uint4*>(&dst[(size_t)(d0 + dd) * L + l0 + cc * 8]) = *reinterpret_cast<uint4*>(u);
  }
}

// ---------------- att (bf16 MFMA): att_b = bf16((fpb @ fhb^T)/clamp(np*nh)) ----
__global__ __launch_bounds__(256) void attb_kernel(const unsigned short* __restrict__ fpb,
                                                   const unsigned short* __restrict__ fhb,
                                                   const float* __restrict__ np_, const float* __restrict__ nh_,
                                                   unsigned short* __restrict__ att_b) {
  __shared__ __align__(16) unsigned short As[128][72];
  __shared__ __align__(16) unsigned short Bs[64][72];
  const int t = threadIdx.x, lane = t & 63, wid = t >> 6;
  const int wm = wid >> 1, wn = wid & 1, r = lane & 15, ks = lane >> 4;
  const int row0 = blockIdx.y * 128, col0 = blockIdx.x * 64;
  f32x4 acc[4][2] = {};
  for (int k0 = 0; k0 < D; k0 += 64) {
#pragma unroll
    for (int i = 0; i < 4; i++) {
      int idx = t + i * 256; int row = idx >> 3, c8 = idx & 7;
      uint4 v = *reinterpret_cast<const uint4*>(&fpb[(size_t)(row0 + row) * D + k0 + c8 * 8]);
      *reinterpret_cast<uint4*>(&As[row][c8 * 8]) = v;
    }
#pragma unroll
    for (int i = 0; i < 2; i++) {
      int idx = t + i * 256; int col = idx >> 3, c8 = idx & 7;
      uint4 v = *reinterpret_cast<const uint4*>(&fhb[(size_t)(col0 + col) * D + k0 + c8 * 8]);
      *reinterpret_cast<uint4*>(&Bs[col][c8 * 8]) = v;
    }
    __syncthreads();
#pragma unroll
    for (int k2 = 0; k2 < 2; k2++) {
      bf16x8 b0 = *reinterpret_cast<const bf16x8*>(&Bs[wn * 32 + r][k2 * 32 + ks * 8]);
      bf16x8 b1 = *reinterpret_cast<const bf16x8*>(&Bs[wn * 32 + 16 + r][k2 * 32 + ks * 8]);
#pragma unroll
      for (int fm = 0; fm < 4; fm++) {
        bf16x8 a = *reinterpret_cast<const bf16x8*>(&As[wm * 64 + fm * 16 + r][k2 * 32 + ks * 8]);
        acc[fm][0] = __builtin_amdgcn_mfma_f32_16x16x32_bf16(a, b0, acc[fm][0], 0, 0, 0);
        acc[fm][1] = __builtin_amdgcn_mfma_f32_16x16x32_bf16(a, b1, acc[fm][1], 0, 0, 0);
      }
    }
    __syncthreads();
  }
#pragma unroll
  for (int fm = 0; fm < 4; fm++)
#pragma unroll
    for (int fn = 0; fn < 2; fn++)
#pragma unroll
      for (int reg = 0; reg < 4; reg++) {
        int l = row0 + wm * 64 + fm * 16 + ks * 4 + reg;
        int c = col0 + wn * 32 + fn * 16 + r;
        float den = np_[l] * nh_[c];
        den = den > EPSF ? den : EPSF;
        att_b[(size_t)l * L + c] = f2b(acc[fm][fn][reg] / den);
      }
}

// ---------------- row sums of att_b (bf16) ----------------
__global__ __launch_bounds__(256) void rowsum_kernel(const unsigned short* __restrict__ att_b, float* __restrict__ rs) {
  int row = blockIdx.x;
  float s = 0.f;
#pragma unroll
  for (int i = 0; i < 2; i++) {
    int chunk = threadIdx.x + i * 256;
    uint4 v = *reinterpret_cast<const uint4*>(&att_b[(size_t)row * L + chunk * 8]);
    const unsigned short* u = reinterpret_cast<const unsigned short*>(&v);
#pragma unroll
    for (int e = 0; e < 8; e++) s += b2f(u[e]);
  }
  for (int off = 32; off > 0; off >>= 1) s += __shfl_down(s, off);
  __shared__ float ps[4];
  if ((threadIdx.x & 63) == 0) ps[threadIdx.x >> 6] = s;
  __syncthreads();
  if (threadIdx.x == 0) rs[row] = ps[0] + ps[1] + ps[2] + ps[3];
}

// ---------------- column sums of att_b (2-stage, deterministic) ----------------
__global__ __launch_bounds__(256) void colpart_kernel(const unsigned short* __restrict__ att_b, float* __restrict__ pr) {
  int bx = blockIdx.x & 15, by = blockIdx.x >> 4;
  int col = bx * 256 + threadIdx.x;
  int r0 = by * 64;
  float s = 0.f;
#pragma unroll 8
  for (int r = 0; r < 64; r++) s += b2f(att_b[(size_t)(r0 + r) * L + col]);
  pr[(size_t)by * L + col] = s;
}
__global__ __launch_bounds__(256) void colsum_kernel(const float* __restrict__ pr, float* __restrict__ cs) {
  int col = blockIdx.x * 256 + threadIdx.x;
  float s = 0.f;
#pragma unroll 8
  for (int k = 0; k < 64; k++) s += pr[(size_t)k * L + col];
  cs[col] = s;
}

// ---------------- amh = (att_b @ fh) / clamp(rs)  [B from fhbt, B^T-form] ----
__global__ __launch_bounds__(256) void amh_kernel(const unsigned short* __restrict__ att_b,
                                                  const unsigned short* __restrict__ fhbt,
                                                  const float* __restrict__ rs, float* __restrict__ outm) {
  __shared__ __align__(16) unsigned short As[128][72];
  __shared__ __align__(16) unsigned short Bs[64][72];
  const int t = threadIdx.x, lane = t & 63, wid = t >> 6;
  const int wm = wid >> 1, wn = wid & 1, r = lane & 15, ks = lane >> 4;
  const int row0 = blockIdx.y * 128, col0 = blockIdx.x * 64;
  f32x4 acc[4][2] = {};
  for (int k0 = 0; k0 < L; k0 += 64) {
#pragma unroll
    for (int i = 0; i < 4; i++) {
      int idx = t + i * 256; int row = idx >> 3, c8 = idx & 7;
      uint4 v = *reinterpret_cast<const uint4*>(&att_b[(size_t)(row0 + row) * L + k0 + c8 * 8]);
      *reinterpret_cast<uint4*>(&As[row][c8 * 8]) = v;
    }
#pragma unroll
    for (int i = 0; i < 2; i++) {
      int idx = t + i * 256; int col = idx >> 3, c8 = idx & 7;
      uint4 v = *reinterpret_cast<const uint4*>(&fhbt[(size_t)(col0 + col) * L + k0 + c8 * 8]);
      *reinterpret_cast<uint4*>(&Bs[col][c8 * 8]) = v;
    }
    __syncthreads();
#pragma unroll
    for (int k2 = 0; k2 < 2; k2++) {
      bf16x8 b0 = *reinterpret_cast<const bf16x8*>(&Bs[wn * 32 + r][k2 * 32 + ks * 8]);
      bf16x8 b1 = *reinterpret_cast<const bf16x8*>(&Bs[wn * 32 + 16 + r][k2 * 32 + ks * 8]);
#pragma unroll
      for (int fm = 0; fm < 4; fm++) {
        bf16x8 a = *reinterpret_cast<const bf16x8*>(&As[wm * 64 + fm * 16 + r][k2 * 32 + ks * 8]);
        acc[fm][0] = __builtin_amdgcn_mfma_f32_16x16x32_bf16(a, b0, acc[fm][0], 0, 0, 0);
        acc[fm][1] = __builtin_amdgcn_mfma_f32_16x16x32_bf16(a, b1, acc[fm][1], 0, 0, 0);
      }
    }
    __syncthreads();
  }
#pragma unroll
  for (int fm = 0; fm < 4; fm++)
#pragma unroll
    for (int fn = 0; fn < 2; fn++)
#pragma unroll
      for (int reg = 0; reg < 4; reg++) {
        int l = row0 + wm * 64 + fm * 16 + ks * 4 + reg;
        int d = col0 + wn * 32 + fn * 16 + r;
        float den = rs[l];
        den = den > EPSF ? den : EPSF;
        outm[(size_t)l * D + d] = acc[fm][fn][reg] / den;
      }
}

// ---------------- amp = (att_b^T @ fp) / clamp(cs) [A transpose-staged] ------
__global__ __launch_bounds__(256) void amp_kernel(const unsigned short* __restrict__ att_b,
                                                  const unsigned short* __restrict__ fpbt,
                                                  const float* __restrict__ cs, float* __restrict__ outm) {
  __shared__ __align__(16) unsigned short At[128 * 72];   // swizzled k within rows
  __shared__ __align__(16) unsigned short Bs[64][72];
  const int t = threadIdx.x, lane = t & 63, wid = t >> 6;
  const int wm = wid >> 1, wn = wid & 1, r = lane & 15, ks = lane >> 4;
  const int row0 = blockIdx.y * 128, col0 = blockIdx.x * 64;
  f32x4 acc[4][2] = {};
  for (int k0 = 0; k0 < L; k0 += 64) {
#pragma unroll
    for (int i = 0; i < 4; i++) {
      int idx = t + i * 256;               // 1024 chunks: 64 kk x 16 c8
      int kk = idx >> 4, c8 = idx & 15;
      uint4 v = *reinterpret_cast<const uint4*>(&att_b[(size_t)(k0 + kk) * L + row0 + c8 * 8]);
      const unsigned short* u = reinterpret_cast<const unsigned short*>(&v);
      int swz = (c8 & 7) << 3;
#pragma unroll
      for (int e = 0; e < 8; e++)
        At[(c8 * 8 + e) * 72 + (kk ^ swz)] = u[e];
    }
#pragma unroll
    for (int i = 0; i < 2; i++) {
      int idx = t + i * 256; int col = idx >> 3, c8 = idx & 7;
      uint4 v = *reinterpret_cast<const uint4*>(&fpbt[(size_t)(col0 + col) * L + k0 + c8 * 8]);
      *reinterpret_cast<uint4*>(&Bs[col][c8 * 8]) = v;
    }
    __syncthreads();
#pragma unroll
    for (int k2 = 0; k2 < 2; k2++) {
      bf16x8 b0 = *reinterpret_cast<const bf16x8*>(&Bs[wn * 32 + r][k2 * 32 + ks * 8]);
      bf16x8 b1 = *reinterpret_cast<const bf16x8*>(&Bs[wn * 32 + 16 + r][k2 * 32 + ks * 8]);
#pragma unroll
      for (int fm = 0; fm < 4; fm++) {
        int j = wm * 64 + fm * 16 + r;
        int off = (k2 * 32 + ks * 8) ^ (((j >> 3) & 7) << 3);
        bf16x8 a = *reinterpret_cast<const bf16x8*>(&At[j * 72 + off]);
        acc[fm][0] = __builtin_amdgcn_mfma_f32_16x16x32_bf16(a, b0, acc[fm][0], 0, 0, 0);
        acc[fm][1] = __builtin_amdgcn_mfma_f32_16x16x32_bf16(a, b1, acc[fm][1], 0, 0, 0);
      }
    }
    __syncthreads();
  }
#pragma unroll
  for (int fm = 0; fm < 4; fm++)
#pragma unroll
    for (int fn = 0; fn < 2; fn++)
#pragma unroll
      for (int reg = 0; reg < 4; reg++) {
        int j = row0 + wm * 64 + fm * 16 + ks * 4 + reg;
        int d = col0 + wn * 32 + fn * 16 + r;
        float den = cs[j];
        den = den > EPSF ? den : EPSF;
        outm[(size_t)j * D + d] = acc[fm][fn][reg] / den;
      }
}

// ---------------- w2 transposed: w2t[d][p] = mp_w[p][d]^2 ----------------
__global__ void w2t_kernel(const float* __restrict__ mpw, float* __restrict__ w2t) {
  int o = blockIdx.x * blockDim.x + threadIdx.x;
  if (o >= PP * D) return;
  int dd = o >> 6, p = o & 63;
  float v = mpw[(size_t)p * D + dd];
  w2t[o] = v * v;
}

// ---------------- multi-perspective weighted cosine ----------------
__global__ __launch_bounds__(64) void match_kernel(const float* __restrict__ fp, const float* __restrict__ fh,
                                                   const float* __restrict__ amh, const float* __restrict__ amp,
                                                   const float* __restrict__ w2t,
                                                   float* __restrict__ match_p, float* __restrict__ match_h) {
  int b = blockIdx.x;
  int which = b >> 12;
  int l = b & (L - 1);
  const float* v1 = (which ? fh : fp) + (size_t)l * D;
  const float* v2 = (which ? amp : amh) + (size_t)l * D;
  __shared__ float s1[D], s2[D];
  int t = threadIdx.x;
#pragma unroll
  for (int i = 0; i < 2; i++) {
    int f4 = t + 64 * i;
    *reinterpret_cast<float4*>(&s1[f4 * 4]) = *reinterpret_cast<const float4*>(&v1[f4 * 4]);
    *reinterpret_cast<float4*>(&s2[f4 * 4]) = *reinterpret_cast<const float4*>(&v2[f4 * 4]);
  }
  __syncthreads();
  float num = 0.f, a1 = 0.f, a2 = 0.f;
  for (int dd = 0; dd < D; dd++) {
    float wv = w2t[dd * PP + t];
    float x = s1[dd], y = s2[dd];
    num += wv * x * y;
    a1 += wv * x * x;
    a2 += wv * y * y;
  }
  float n1 = fmaxf(sqrtf(a1), EPSF), n2 = fmaxf(sqrtf(a2), EPSF);
  float* outm = which ? match_h : match_p;
  outm[(size_t)l * PP + t] = num / (n1 * n2);
}

// ---------------- gx = match @ w_ih^T + (b_ih + b_hh), time-reversed for odd dirs ----------------
__global__ __launch_bounds__(512) void gx_kernel(const float* __restrict__ match_p, const float* __restrict__ match_h,
                                                 const float* __restrict__ wih_f, const float* __restrict__ wih_r,
                                                 const float* __restrict__ bih_f, const float* __restrict__ bhh_f,
                                                 const float* __restrict__ bih_r, const float* __restrict__ bhh_r,
                                                 float* __restrict__ gx) {
  int b = blockIdx.x;
  int dir = b >> 9;
  int chunk = b & 511;
  const float* m_src = (dir < 2) ? match_p : match_h;
  const float* wih = (dir & 1) ? wih_r : wih_f;
  const float* bi = (dir & 1) ? bih_r : bih_f;
  const float* bh = (dir & 1) ? bhh_r : bhh_f;
  __shared__ float m[8][PP];
  int t = threadIdx.x;
  {
    int tt = t >> 6, p = t & 63;
    int tstep = chunk * 8 + tt;
    int row = (dir & 1) ? (L - 1 - tstep) : tstep;
    m[tt][p] = m_src[(size_t)row * PP + p];
  }
  __syncthreads();
  int j = t;
  float bias = bi[j] + bh[j];
  float acc[8];
#pragma unroll
  for (int tt = 0; tt < 8; tt++) acc[tt] = bias;
  for (int p = 0; p < PP; p++) {
    float wv = wih[(size_t)j * PP + p];
#pragma unroll
    for (int tt = 0; tt < 8; tt++) acc[tt] += wv * m[tt][p];
  }
#pragma unroll
  for (int tt = 0; tt < 8; tt++)
    gx[((size_t)dir * L + chunk * 8 + tt) * 512 + j] = acc[tt];
}

// opaque 16B load (r8/r9): inline-asm def, cannot be rematerialized; vmcnt(0)
// embedded so the outputs are data-complete at the def (rule #18 safe).
__device__ __forceinline__ float4 load4_opaque(const float* p) {
  float4 v;
  asm volatile("global_load_dwordx4 %0, %1, off\n\ts_waitcnt vmcnt(0)"
               : "=v"(v) : "v"(p));
  return v;
}

// cross-lane XOR exchange on the VALU (DPP), not the DS pipe.
// 0xB1 = quad_perm [1,0,3,2] (xor1); 0x4E = quad_perm [2,3,0,1] (xor2);
// 0x128 = row_ror:8 == xor8 within each 16-lane row.
template <int CTRL>
__device__ __forceinline__ float xdpp(float x) {
  return __int_as_float(__builtin_amdgcn_mov_dpp(__float_as_int(x), CTRL, 0xf, 0xf, true));
}

// ---------------- 4 sequential LSTMs (round-9 configuration, verbatim) ------
// Best measured LSTM variant (3147 us): VALU fp32 matvec, DPP compacting
// butterfly (1 DS shuffle/step), h at stride-12 conflict-free layout, phase-2
// on tid<128, two lgkm-drained barriers. r10/r11 MFMA = 3365; r12/r14
// gate-grouped 1-barrier = 17-50ms (twice; abandoned). The ~1850 cyc/step
// floor is sync/latency-structural, invariant to engine and weight residency.
__global__ __attribute__((amdgpu_waves_per_eu(4, 4))) __launch_bounds__(1024)
void lstm_kernel(const float* __restrict__ gx,
                 const float* __restrict__ whh_f, const float* __restrict__ whh_r,
                 float* __restrict__ out) {
  const int dir = blockIdx.x;
  const float* __restrict__ whh = (dir & 1) ? whh_r : whh_f;
  const int tid = threadIdx.x;
  const int lane = tid & 63;
  const int wv = tid >> 6;            // wave 0..15
  const int sec = lane >> 4;          // 16-lane section 0..3
  const int gam = lane & 15;          // γ
  const int o_of = (gam & 1) | (((gam >> 1) & 1) << 1) | (((gam >> 3) & 1) << 2);
  const int jsec = wv * 32 + sec * 8;
  const int jmine = jsec + o_of;      // output this lane finalizes
  const int kbase = gam * 8;          // k-octet

  float4 w4[8][2];
#pragma unroll
  for (int jj = 0; jj < 8; jj++) {
    w4[jj][0] = load4_opaque(&whh[(size_t)(jsec + jj) * HH + kbase]);
    w4[jj][1] = load4_opaque(&whh[(size_t)(jsec + jj) * HH + kbase + 4]);
  }

  __shared__ __align__(16) float h_pad[16 * 12];  // octet κ at float offset 12κ
  __shared__ float act[512];
  if (tid < 192) h_pad[tid] = 0.f;
  __syncthreads();

  const float* __restrict__ gsrc = gx + (size_t)dir * L * 512;
  float gval = gsrc[jmine];
  const int m = tid & 127;
  const int is_g_gate = ((jmine >> 7) == 2);    // wave-uniform
  const int s0b = gam & 1, s1b = gam & 2, s3b = gam & 8;
  const int hoff = gam * 12;
  const int hwr = (m >> 3) * 12 + (m & 7);      // phase-2 write slot
  float c = 0.f, h = 0.f;

  for (int t = 0; t < L; t++) {
    float gnext = (t + 1 < L) ? gsrc[(size_t)(t + 1) * 512 + jmine] : 0.f;
    float4 hf0 = *reinterpret_cast<const float4*>(&h_pad[hoff]);
    float4 hf1 = *reinterpret_cast<const float4*>(&h_pad[hoff + 4]);
    float acc[8];
#pragma unroll
    for (int jj = 0; jj < 8; jj++) {
      float s0 = w4[jj][0].x * hf0.x;
      float s1 = w4[jj][0].y * hf0.y;
      s0 = fmaf(w4[jj][0].z, hf0.z, s0);
      s1 = fmaf(w4[jj][0].w, hf0.w, s1);
      s0 = fmaf(w4[jj][1].x, hf1.x, s0);
      s1 = fmaf(w4[jj][1].y, hf1.y, s1);
      s0 = fmaf(w4[jj][1].z, hf1.z, s0);
      s1 = fmaf(w4[jj][1].w, hf1.w, s1);
      acc[jj] = s0 + s1;
    }
    // compacting butterfly: xor1, xor2 (quad_perm), xor8 (row_ror:8) — VALU
    float r4[4];
#pragma unroll
    for (int i = 0; i < 4; i++) {
      float keep = s0b ? acc[2 * i + 1] : acc[2 * i];
      float send = s0b ? acc[2 * i] : acc[2 * i + 1];
      r4[i] = keep + xdpp<0xB1>(send);
    }
    float r2[2];
#pragma unroll
    for (int u = 0; u < 2; u++) {
      float keep = s1b ? r4[2 * u + 1] : r4[2 * u];
      float send = s1b ? r4[2 * u] : r4[2 * u + 1];
      r2[u] = keep + xdpp<0x4E>(send);
    }
    float keep1 = s3b ? r2[1] : r2[0];
    float send1 = s3b ? r2[0] : r2[1];
    float r1 = keep1 + xdpp<0x128>(send1);
    // k-half combine (γ2): the single remaining DS shuffle
    float z = r1 + __shfl_xor(r1, 4) + gval;
    float a;
    if (is_g_gate) {
      float e = __expf(2.f * z);
      a = 1.f - 2.f / (e + 1.f);
    } else {
      a = 1.f / (1.f + __expf(-z));
    }
    act[jmine] = a;                       // γ2-twins write same value
    __syncthreads();
    if (tid < HH) {                       // 2 waves only
      float iv = act[m], fv = act[HH + m], gg = act[2 * HH + m], ov = act[3 * HH + m];
      c = fv * c + iv * gg;
      float e2 = __expf(2.f * c);
      h = ov * (1.f - 2.f / (e2 + 1.f));
      h_pad[hwr] = h;
    }
    __syncthreads();
    gval = gnext;
  }
  if (tid < HH) out[dir * HH + tid] = h;
}

extern "C" void kernel_launch(void* const* d_in, const int* in_sizes, int n_in,
                              void* d_out, int out_size, void* d_ws, size_t ws_size,
                              hipStream_t stream) {
  const float* fp    = (const float*)d_in[0];
  const float* fh    = (const float*)d_in[1];
  const float* mpw   = (const float*)d_in[2];
  const float* wih_f = (const float*)d_in[3];
  const float* whh_f = (const float*)d_in[4];
  const float* bih_f = (const float*)d_in[5];
  const float* bhh_f = (const float*)d_in[6];
  const float* wih_r = (const float*)d_in[7];
  const float* whh_r = (const float*)d_in[8];
  const float* bih_r = (const float*)d_in[9];
  const float* bhh_r = (const float*)d_in[10];
  float* out = (float*)d_out;
  float* ws = (float*)d_ws;

  // workspace layout (float units)
  size_t np_off   = 0;                          // 4096
  size_t nh_off   = np_off + L;                 // 4096
  size_t rs_off   = nh_off + L;                 // 4096
  size_t cs_off   = rs_off + L;                 // 4096
  size_t w2_off   = cs_off + L;                 // 32768
  size_t amh_off  = w2_off + (size_t)PP * D;    // 2097152
  size_t amp_off  = amh_off + (size_t)L * D;    // 2097152
  size_t mp_off   = amp_off + (size_t)L * D;    // 262144
  size_t mh_off   = mp_off + (size_t)L * PP;    // 262144
  size_t pr_off   = mh_off + (size_t)L * PP;    // 262144
  size_t fpb_off  = pr_off + (size_t)64 * L;    // bf16 buffers (L*D/2 floats each)
  size_t fhb_off  = fpb_off + (size_t)L * D / 2;
  size_t fpbt_off = fhb_off + (size_t)L * D / 2;
  size_t fhbt_off = fpbt_off + (size_t)L * D / 2;
  size_t attb_off = fhbt_off + (size_t)L * D / 2;  // L*L bf16 = L*L/2 floats
  size_t gx_off   = attb_off;                      // alias: gx reuses att_b region
  size_t total    = attb_off + (size_t)L * L / 2;
  {
    size_t gx_end = gx_off + (size_t)4 * L * 512;
    if (gx_end > total) total = gx_end;
  }
  if (ws_size < total * sizeof(float)) return;  // workspace too small — bail safely

  float* np_  = ws + np_off;
  float* nh_  = ws + nh_off;
  float* rs   = ws + rs_off;
  float* cs   = ws + cs_off;
  float* w2t  = ws + w2_off;
  float* amh  = ws + amh_off;
  float* amp  = ws + amp_off;
  float* mtp  = ws + mp_off;
  float* mth  = ws + mh_off;
  float* pr   = ws + pr_off;
  unsigned short* fpb  = (unsigned short*)(ws + fpb_off);
  unsigned short* fhb  = (unsigned short*)(ws + fhb_off);
  unsigned short* fpbt = (unsigned short*)(ws + fpbt_off);
  unsigned short* fhbt = (unsigned short*)(ws + fhbt_off);
  unsigned short* attb = (unsigned short*)(ws + attb_off);
  float* gx   = ws + gx_off;

  norms_kernel<<<2 * L, 64, 0, stream>>>(fp, fh, np_, nh_);
  cast_kernel<<<dim3((L * D) / (256 * 8), 2), 256, 0, stream>>>(fp, fh, fpb, fhb);
  transp_kernel<<<dim3(D / 64, L / 64, 2), 256, 0, stream>>>(fp, fh, fpbt, fhbt);
  attb_kernel<<<dim3(L / 64, L / 128), 256, 0, stream>>>(fpb, fhb, np_, nh_, attb);
  rowsum_kernel<<<L, 256, 0, stream>>>(attb, rs);
  colpart_kernel<<<1024, 256, 0, stream>>>(attb, pr);
  colsum_kernel<<<16, 256, 0, stream>>>(pr, cs);
  amh_kernel<<<dim3(D / 64, L / 128), 256, 0, stream>>>(attb, fhbt, rs, amh);
  amp_kernel<<<dim3(D / 64, L / 128), 256, 0, stream>>>(attb, fpbt, cs, amp);
  w2t_kernel<<<(PP * D + 255) / 256, 256, 0, stream>>>(mpw, w2t);
  match_kernel<<<2 * L, 64, 0, stream>>>(fp, fh, amh, amp, w2t, mtp, mth);
  gx_kernel<<<4 * (L / 8), 512, 0, stream>>>(mtp, mth, wih_f, wih_r, bih_f, bhh_f, bih_r, bhh_r, gx);
  lstm_kernel<<<4, 1024, 0, stream>>>(gx, whh_f, whh_r, out);
}